// Round 1
// baseline (1642.023 us; speedup 1.0000x reference)
//
#include <hip/hip_runtime.h>
#include <hip/hip_bf16.h>

// trackletGNN: 3x edge-conv + MLP head.
// R8: latency/occupancy attack on the eagg kernels (were 2x314us, Occ 35%,
// VALU 8% -> latency-bound on two dependent random gathers at 16 waves/CU).
//  (a) bucket 1024 -> 512 nodes: acc LDS 36.9KB -> 18.4KB, 4 -> 8 blocks/CU
//      (32 waves = HW cap); __launch_bounds__(256,8) pins VGPR <= 64.
//  (b) node features packed into ONE 32B-aligned record (uint4 pair): each
//      edge gather touches exactly one 64B line. Kills the separate 2B hB
//      gather stream (~150-200MB/dispatch of L2-thrash misses).
//  (c) NBUCK 1465 -> 2930 pushes k_part static LDS past 64KB, so the 16KB
//      per-slot gad[] is replaced by a 12-step binary search over cur[]
//      (post-phase-3 cur[] is exactly the local end-offset array).
// Fixed-point LDS accumulation is integer-exact -> bucket-order change
// cannot move absmax. Workspace ~195MB (perm 96 + 2x packed 48 + xb 3).

#define NNODES 1500000
#define NEDGES 12000000
#define NTRACK 250000
#define BSH    9           // log2(bucket size)
#define BSZ    512         // nodes per agg bucket
#define BMASK  511u
#define NBUCK  2930        // ceil(NNODES/512)
#define PCHUNK 4096        // edges per k_part block (LDS-sorted)
#define PBLK   2930        // ceil(NEDGES/PCHUNK)
#define HCHUNK 32768       // edges per k_bhist block
#define HBLK   367         // ceil(NEDGES/HCHUNK)
#define SRCMASK 0x1FFFFFu  // 21 bits
#define FXSCALE 16777216.f // 2^24
#define FXINV   (1.f / 16777216.f)

typedef unsigned int   u32;
typedef unsigned short u16;

static __device__ __forceinline__ float b2f(u32 v) {
    union { float f; u32 u; } x; x.u = v << 16; return x.f;
}
static __device__ __forceinline__ u16 f2b(float f) {
    __hip_bfloat16 h = __float2bfloat16(f);
    return *reinterpret_cast<u16*>(&h);
}
static __device__ __forceinline__ float ldw(const void* p, int i, int isf32) {
    return isf32 ? ((const float*)p)[i] : b2f((u32)((const u16*)p)[i]);
}
static __device__ __forceinline__ int fx(float f) {
    return (int)rintf(f * FXSCALE);
}

// ---------------- dtype probe ----------------

__global__ void k_detect(const u16* a, const u16* b, const u16* c,
                         const u16* d, const u16* e, const u16* f,
                         int* flag) {
    if (blockIdx.x == 0 && threadIdx.x == 0) {
        int isf32 = 0;
        const u16* ps[6] = {a, b, c, d, e, f};
        const int  ns[6] = {9, 9, 9, 9, 9, 8};
        for (int k = 0; k < 6; k++)
            for (int i = 0; i < ns[k]; i++) {
                float v = b2f((u32)ps[k][i]);
                if (!(fabsf(v) < 1.0e3f)) isf32 = 1;   // catches NaN/Inf too
            }
        *flag = isf32;
    }
}

// ------------- x -> bf16 table (3 MB, fits per-XCD L2 for layer 1) -------

__global__ __launch_bounds__(256) void k_xcast(const void* __restrict__ x,
                                               u16* __restrict__ xb,
                                               const int* __restrict__ flag) {
    int isf32 = *flag;
    int n = blockIdx.x * 256 + threadIdx.x;
    if (n < NNODES)
        xb[n] = isf32 ? f2b(((const float*)x)[n]) : ((const u16*)x)[n];
}

// ---------------- bucket histogram + scan (exact, unpadded) --------------

__global__ __launch_bounds__(512) void k_bhist(const int* __restrict__ dst,
                                               int* __restrict__ gh) {
    __shared__ u32 h[NBUCK];
    int t = threadIdx.x;
    for (int b = t; b < NBUCK; b += 512) h[b] = 0;
    __syncthreads();
    int c0 = blockIdx.x * HCHUNK;
#pragma unroll 4
    for (int i = 0; i < HCHUNK / 512; i++) {
        int e = c0 + i * 512 + t;
        if (e < NEDGES) atomicAdd(&h[((u32)dst[e]) >> BSH], 1u);
    }
    __syncthreads();
    for (int b = t; b < NBUCK; b += 512) {
        u32 c = h[b];
        if (c) atomicAdd((u32*)&gh[b], c);
    }
}

__global__ __launch_bounds__(256) void k_bscan(const int* __restrict__ gh,
                                               int* __restrict__ bstart,
                                               int* __restrict__ gcur) {
    __shared__ u32 sd[256];
    __shared__ u32 carry;
    int t = threadIdx.x;
    if (t == 0) carry = 0;
    __syncthreads();
    for (int c0 = 0; c0 < NBUCK; c0 += 256) {
        int b = c0 + t;
        u32 v = (b < NBUCK) ? (u32)gh[b] : 0;
        sd[t] = v; __syncthreads();
        for (int o = 1; o < 256; o <<= 1) {
            u32 a = (t >= o) ? sd[t - o] : 0;
            __syncthreads();
            sd[t] += a;
            __syncthreads();
        }
        u32 excl = carry + sd[t] - v;
        if (b < NBUCK) { bstart[b] = (int)excl; gcur[b] = (int)excl; }
        __syncthreads();
        if (t == 255) carry += sd[255];
        __syncthreads();
    }
    if (t == 0) bstart[NBUCK] = NEDGES;
}

// ---- partition: chunk-local LDS counting sort + ordered coalesced flush ----
// LDS: cur 11.7K + gbA 11.7K + rec 32K + sd 2K = 58.3KB (< 64KB static cap).
// Flush resolves each slot's bucket by binary search over cur[] (end offsets).

__global__ __launch_bounds__(512) void k_part(const int* __restrict__ src,
                                              const int* __restrict__ dst,
                                              const void* __restrict__ attr,
                                              int* __restrict__ gcur,
                                              uint2* __restrict__ perm,
                                              const int* __restrict__ flag) {
    __shared__ int   cur[NBUCK];    // hist -> local exclusive start -> cursor
    __shared__ int   gbA[NBUCK];    // global run base minus local start
    __shared__ uint2 rec[PCHUNK];   // bucket-grouped records
    __shared__ u32   sd[512];
    __shared__ u32   carryS;
    int isf32 = *flag;
    int t = threadIdx.x;
    int c0 = blockIdx.x * PCHUNK;
    int chunkN = NEDGES - c0; if (chunkN > PCHUNK) chunkN = PCHUNK;

    for (int b = t; b < NBUCK; b += 512) cur[b] = 0;
    if (t == 0) carryS = 0;
    __syncthreads();

    // phase 1: histogram; keep src/dst in registers
    int ds_[8], sr_[8];
#pragma unroll
    for (int k = 0; k < 8; k++) {
        int e = c0 + k * 512 + t;
        if (e < NEDGES) {
            ds_[k] = dst[e];
            sr_[k] = src[e];
            atomicAdd((u32*)&cur[((u32)ds_[k]) >> BSH], 1u);
        } else { ds_[k] = -1; sr_[k] = 0; }
    }
    __syncthreads();

    // phase 2: exclusive scan of cur + global run reservation
    for (int b0 = 0; b0 < NBUCK; b0 += 512) {
        int b = b0 + t;
        u32 v = (b < NBUCK) ? (u32)cur[b] : 0;
        sd[t] = v; __syncthreads();
        for (int o = 1; o < 512; o <<= 1) {
            u32 a = (t >= o) ? sd[t - o] : 0;
            __syncthreads();
            sd[t] += a;
            __syncthreads();
        }
        u32 excl = carryS + sd[t] - v;
        if (b < NBUCK) {
            cur[b] = (int)excl;
            if (v) gbA[b] = atomicAdd(&gcur[b], (int)v) - (int)excl;
        }
        __syncthreads();
        if (t == 511) carryS += sd[511];
        __syncthreads();
    }

    // phase 3: scatter records into LDS
#pragma unroll
    for (int k = 0; k < 8; k++) {
        int e = c0 + k * 512 + t;
        if (e < NEDGES) {
            u32 d  = (u32)ds_[k];
            u32 fb = d >> BSH;
            u32 ap;
            if (isf32) {
                float2 a = ((const float2*)attr)[e];
                ap = (u32)f2b(a.x) | ((u32)f2b(a.y) << 16);
            } else {
                ap = ((const u32*)attr)[e];
            }
            int slot = atomicAdd(&cur[fb], 1);
            uint2 r; r.x = ((u32)sr_[k]) | ((d & BMASK) << 21); r.y = ap;
            rec[slot] = r;
        }
    }
    __syncthreads();

    // phase 4: ordered flush -- slot-consecutive => line-burst writes.
    // bucket(slot) = lower_bound over cur[] (now per-bucket END offsets).
#pragma unroll
    for (int j = 0; j < 8; j++) {
        int s = j * 512 + t;
        if (s < chunkN) {
            int lo = 0, hi = NBUCK - 1;
            while (lo < hi) {
                int mid = (lo + hi) >> 1;
                if (cur[mid] > s) hi = mid; else lo = mid + 1;
            }
            perm[gbA[lo] + s] = rec[s];
        }
    }
}

// ---- layer 1 (edge-centric): gather bf16 x (L2-resident), fx LDS acc ----
// Output: packed 32B/node record {h0..h7 | h8,0,0,0} for single-line gathers.

__global__ __launch_bounds__(256, 8) void k_eagg1(
        const int* __restrict__ bstart, const uint2* __restrict__ perm,
        const u16* __restrict__ xb,
        const void* Wx, const void* bx, const void* We, const void* be,
        const void* Wo, const void* bo, const void* Wxn, const void* bxn,
        uint4* __restrict__ hO, const int* __restrict__ flag) {
    __shared__ int acc[BSZ * 9];
    __shared__ float sWx[9], sbx[9], sWe[18], sbe[9], sWo[81], sbo[9], sWxn[81], sbxn[9];
    int isf32 = *flag;
    int t = threadIdx.x;
    if (t < 9)  sWx[t]  = ldw(Wx,  t, isf32);
    if (t < 9)  sbx[t]  = ldw(bx,  t, isf32);
    if (t < 18) sWe[t]  = ldw(We,  t, isf32);
    if (t < 9)  sbe[t]  = ldw(be,  t, isf32);
    if (t < 81) sWo[t]  = ldw(Wo,  t, isf32);
    if (t < 9)  sbo[t]  = ldw(bo,  t, isf32);
    if (t < 81) sWxn[t] = ldw(Wxn, t, isf32);
    if (t < 9)  sbxn[t] = ldw(bxn, t, isf32);
    for (int i = t; i < BSZ * 9; i += 256) acc[i] = 0;
    __syncthreads();

    int b = blockIdx.x;
    int r0 = bstart[b], r1 = bstart[b + 1];
    for (int i = r0 + t; i < r1; i += 256) {
        uint2 rec = perm[i];
        int   l   = (int)((rec.x >> 21) & BMASK);
        float xs  = b2f((u32)xb[rec.x & SRCMASK]);
        float a0  = b2f(rec.y & 0xffffu);
        float a1  = b2f(rec.y >> 16);
        int* ap = &acc[l * 9];
#pragma unroll
        for (int j = 0; j < 9; j++) {
            float e  = fmaf(a0, sWe[2 * j], fmaf(a1, sWe[2 * j + 1], sbe[j]));
            float hh = fmaf(xs, sWx[j], sbx[j]);
            atomicAdd(&ap[j], fx(hh * e));     // native ds_add_u32
        }
    }
    __syncthreads();

    for (int l = t; l < BSZ; l += 256) {
        int n = b * BSZ + l;
        if (n >= NNODES) break;
        float av[9];
#pragma unroll
        for (int j = 0; j < 9; j++) av[j] = (float)acc[l * 9 + j] * FXINV;
        float o[9];
#pragma unroll
        for (int k = 0; k < 9; k++) {
            float v = sbo[k];
#pragma unroll
            for (int j = 0; j < 9; j++) v = fmaf(av[j], sWo[k * 9 + j], v);
            o[k] = fmaxf(v, 0.f);
        }
        u16 hv[9];
#pragma unroll
        for (int j = 0; j < 9; j++) {
            float v = sbxn[j];
#pragma unroll
            for (int k = 0; k < 9; k++) v = fmaf(o[k], sWxn[j * 9 + k], v);
            hv[j] = f2b(v);
        }
        uint4 q0, q1;
        q0.x = (u32)hv[0] | ((u32)hv[1] << 16);
        q0.y = (u32)hv[2] | ((u32)hv[3] << 16);
        q0.z = (u32)hv[4] | ((u32)hv[5] << 16);
        q0.w = (u32)hv[6] | ((u32)hv[7] << 16);
        q1.x = (u32)hv[8]; q1.y = 0; q1.z = 0; q1.w = 0;
        size_t p = (size_t)n << 1;
        hO[p] = q0; hO[p + 1] = q1;
    }
}

// ---- layers 2/3 (edge-centric): single 32B-record gather, fx LDS acc ----

template <int OUTF, bool FUSE_NEXT>
__global__ __launch_bounds__(256, 8) void k_eagg(
        const int* __restrict__ bstart, const uint2* __restrict__ perm,
        const uint4* __restrict__ hT,
        const void* We, const void* be, const void* Wo, const void* bo,
        const void* Wxn, const void* bxn,
        uint4* __restrict__ oT, const int* __restrict__ flag) {
    __shared__ int acc[BSZ * 9];
    __shared__ float sWe[18], sbe[9], sWo[OUTF * 9], sbo[OUTF];
    __shared__ float sWxn[FUSE_NEXT ? 81 : 1], sbxn[FUSE_NEXT ? 9 : 1];
    int isf32 = *flag;
    int t = threadIdx.x;
    if (t < 18)       sWe[t] = ldw(We, t, isf32);
    if (t < 9)        sbe[t] = ldw(be, t, isf32);
    if (t < OUTF * 9) sWo[t] = ldw(Wo, t, isf32);
    if (t < OUTF)     sbo[t] = ldw(bo, t, isf32);
    if constexpr (FUSE_NEXT) {
        if (t < 81) sWxn[t] = ldw(Wxn, t, isf32);
        if (t < 9)  sbxn[t] = ldw(bxn, t, isf32);
    }
    for (int i = t; i < BSZ * 9; i += 256) acc[i] = 0;
    __syncthreads();

    int b = blockIdx.x;
    int r0 = bstart[b], r1 = bstart[b + 1];
    for (int i = r0 + t; i < r1; i += 256) {
        uint2 rec = perm[i];
        int   s   = (int)(rec.x & SRCMASK);
        const uint4* hp = hT + ((size_t)s << 1);
        uint4 qa  = hp[0];                // one 64B line per edge (32B-aligned)
        u32   qb  = hp[1].x;
        int   l   = (int)((rec.x >> 21) & BMASK);
        float a0  = b2f(rec.y & 0xffffu);
        float a1  = b2f(rec.y >> 16);
        float ev[9];
#pragma unroll
        for (int j = 0; j < 9; j++)       // edge-linear: independent of gather
            ev[j] = fmaf(a0, sWe[2 * j], fmaf(a1, sWe[2 * j + 1], sbe[j]));
        float h[9];
        h[0] = b2f(qa.x & 0xffffu); h[1] = b2f(qa.x >> 16);
        h[2] = b2f(qa.y & 0xffffu); h[3] = b2f(qa.y >> 16);
        h[4] = b2f(qa.z & 0xffffu); h[5] = b2f(qa.z >> 16);
        h[6] = b2f(qa.w & 0xffffu); h[7] = b2f(qa.w >> 16);
        h[8] = b2f(qb & 0xffffu);
        int* ap = &acc[l * 9];
#pragma unroll
        for (int j = 0; j < 9; j++)
            atomicAdd(&ap[j], fx(h[j] * ev[j]));
    }
    __syncthreads();

    for (int l = t; l < BSZ; l += 256) {
        int n = b * BSZ + l;
        if (n >= NNODES) break;
        float av[9];
#pragma unroll
        for (int j = 0; j < 9; j++) av[j] = (float)acc[l * 9 + j] * FXINV;
        float o[OUTF];
#pragma unroll
        for (int k = 0; k < OUTF; k++) {
            float v = sbo[k];
#pragma unroll
            for (int j = 0; j < 9; j++) v = fmaf(av[j], sWo[k * 9 + j], v);
            o[k] = fmaxf(v, 0.f);
        }
        if constexpr (FUSE_NEXT) {
            u16 hv[9];
#pragma unroll
            for (int j = 0; j < 9; j++) {
                float v = sbxn[j];
#pragma unroll
                for (int k = 0; k < OUTF; k++) v = fmaf(o[k], sWxn[j * 9 + k], v);
                hv[j] = f2b(v);
            }
            uint4 q0, q1;
            q0.x = (u32)hv[0] | ((u32)hv[1] << 16);
            q0.y = (u32)hv[2] | ((u32)hv[3] << 16);
            q0.z = (u32)hv[4] | ((u32)hv[5] << 16);
            q0.w = (u32)hv[6] | ((u32)hv[7] << 16);
            q1.x = (u32)hv[8]; q1.y = 0; q1.z = 0; q1.w = 0;
            size_t p = (size_t)n << 1;
            oT[p] = q0; oT[p + 1] = q1;
        } else {
            uint2 q;
            q.x = (u32)f2b(o[0]) | ((u32)f2b(o[1]) << 16);
            q.y = (u32)f2b(o[2]) | ((u32)f2b(o[3]) << 16);
            ((uint2*)oT)[n] = q;   // f table: 8B/node
        }
    }
}

// ---------------- head MLP + log_softmax ----------------

__global__ __launch_bounds__(256) void k_head(
        const u16* __restrict__ f,
        const void* W1, const void* b1, const void* W2, const void* b2,
        void* __restrict__ out, const int* __restrict__ flag) {
    __shared__ float sW1[192], sb1[8], sW2[32], sb2[4];
    int isf32 = *flag;
    int t = threadIdx.x;
    if (t < 192) sW1[t] = ldw(W1, t, isf32);
    if (t < 8)   sb1[t] = ldw(b1, t, isf32);
    if (t < 32)  sW2[t] = ldw(W2, t, isf32);
    if (t < 4)   sb2[t] = ldw(b2, t, isf32);
    __syncthreads();

    int tr = blockIdx.x * 256 + t;
    if (tr >= NTRACK) return;

    const uint4* fp = (const uint4*)(f + (size_t)tr * 24);
    uint4 A = fp[0], B = fp[1], C = fp[2];
    u32 w[12] = {A.x, A.y, A.z, A.w, B.x, B.y, B.z, B.w, C.x, C.y, C.z, C.w};
    float in[24];
#pragma unroll
    for (int i = 0; i < 12; i++) {
        in[2 * i]     = b2f(w[i] & 0xffffu);
        in[2 * i + 1] = b2f(w[i] >> 16);
    }

    float z1[8];
#pragma unroll
    for (int o = 0; o < 8; o++) {
        float v = sb1[o];
#pragma unroll
        for (int i = 0; i < 24; i++) v = fmaf(in[i], sW1[o * 24 + i], v);
        z1[o] = fmaxf(v, 0.f);
    }
    float z2[4];
#pragma unroll
    for (int c = 0; c < 4; c++) {
        float v = sb2[c];
#pragma unroll
        for (int o = 0; o < 8; o++) v = fmaf(z1[o], sW2[c * 8 + o], v);
        z2[c] = v;
    }
    float m = fmaxf(fmaxf(z2[0], z2[1]), fmaxf(z2[2], z2[3]));
    float s = 0.f;
#pragma unroll
    for (int c = 0; c < 4; c++) s += expf(z2[c] - m);
    float l = logf(s) + m;

    if (isf32) {
        float4 q; q.x = z2[0] - l; q.y = z2[1] - l; q.z = z2[2] - l; q.w = z2[3] - l;
        ((float4*)((float*)out + (size_t)tr * 4))[0] = q;
    } else {
        uint2 q;
        q.x = (u32)f2b(z2[0] - l) | ((u32)f2b(z2[1] - l) << 16);
        q.y = (u32)f2b(z2[2] - l) | ((u32)f2b(z2[3] - l) << 16);
        ((uint2*)((u16*)out + (size_t)tr * 4))[0] = q;
    }
}

// ---------------- host ----------------

extern "C" void kernel_launch(void* const* d_in, const int* in_sizes, int n_in,
                              void* d_out, int out_size, void* d_ws, size_t ws_size,
                              hipStream_t stream) {
    const void* X    = d_in[0];
    const int* eidx  = (const int*)d_in[1];
    const void* eattr= d_in[2];
    const void *WX1 = d_in[3],  *BX1 = d_in[4];
    const void *WE1 = d_in[5],  *BE1 = d_in[6];
    const void *WO1 = d_in[7],  *BO1 = d_in[8];
    const void *WX2 = d_in[9],  *BX2 = d_in[10];
    const void *WE2 = d_in[11], *BE2 = d_in[12];
    const void *WO2 = d_in[13], *BO2 = d_in[14];
    const void *WX3 = d_in[15], *BX3 = d_in[16];
    const void *WE3 = d_in[17], *BE3 = d_in[18];
    const void *WO3 = d_in[19], *BO3 = d_in[20];
    const void *W1  = d_in[21], *B1  = d_in[22];
    const void *W2  = d_in[23], *B2  = d_in[24];

    const int* src = eidx;
    const int* dst = eidx + NEDGES;

    // workspace layout (~195 MB)
    char* w = (char*)d_ws;
    size_t off = 0;
    auto take = [&](size_t bytes) -> void* {
        void* p = w + off;
        off += (bytes + 255) & ~(size_t)255;
        return p;
    };
    int*   flag   = (int*)take(256);
    int*   gh     = (int*)take((size_t)NBUCK * 4);
    int*   bstart = (int*)take((size_t)(NBUCK + 1) * 4);
    int*   gcur   = (int*)take((size_t)NBUCK * 4);
    u16*   xb     = (u16*)take((size_t)NNODES * 2);        // 3 MB bf16 x
    uint2* perm   = (uint2*)take((size_t)NEDGES * 8);      // 96 MB exact
    uint4* h2     = (uint4*)take((size_t)NNODES * 32);     // 48 MB packed
    uint4* h3     = (uint4*)take((size_t)NNODES * 32);     // 48 MB packed
    u16*   f      = (u16*)h2;  // layer-3 output (12 MB) reuses h2 (dead by then)
    (void)ws_size; (void)n_in; (void)in_sizes; (void)out_size;

    const int NB = (NNODES + 255) / 256;
    const int TB = (NTRACK + 255) / 256;

    hipMemsetAsync(gh, 0, (size_t)NBUCK * 4, stream);

    k_detect <<<1,    64,  0, stream>>>((const u16*)BX1, (const u16*)BE1, (const u16*)BO1,
                                        (const u16*)BX2, (const u16*)BE2, (const u16*)B1, flag);
    k_xcast  <<<NB,   256, 0, stream>>>(X, xb, flag);
    k_bhist  <<<HBLK, 512, 0, stream>>>(dst, gh);
    k_bscan  <<<1,    256, 0, stream>>>(gh, bstart, gcur);
    k_part   <<<PBLK, 512, 0, stream>>>(src, dst, eattr, gcur, perm, flag);

    k_eagg1        <<<NBUCK, 256, 0, stream>>>(bstart, perm, xb,
                                               WX1, BX1, WE1, BE1, WO1, BO1, WX2, BX2,
                                               h2, flag);
    k_eagg<9,true> <<<NBUCK, 256, 0, stream>>>(bstart, perm, h2,
                                               WE2, BE2, WO2, BO2, WX3, BX3,
                                               h3, flag);
    k_eagg<4,false><<<NBUCK, 256, 0, stream>>>(bstart, perm, h3,
                                               WE3, BE3, WO3, BO3, WO3, BO3,
                                               (uint4*)f, flag);
    k_head         <<<TB,    256, 0, stream>>>(f, W1, B1, W2, B2, d_out, flag);
}

// Round 2
// 1043.525 us; speedup vs baseline: 1.5735x; 1.5735x over previous
//
#include <hip/hip_runtime.h>
#include <hip/hip_bf16.h>

// trackletGNN: 3x edge-conv + MLP head.
// R9: revert R8's spill regression, attack gather MISS TRAFFIC instead.
// R8 post-mortem: launch_bounds(256,8) -> VGPR forced 32 -> ~600MB/dispatch
// scratch round-trips (FETCH+WRITE both +600MB); 32B padded records grew the
// table 27->48MB. Occupancy x2 bought only +12% service rate -> eagg is
// SATURATED on the L2-miss path, not latency-bound.
// R9: (a) eagg back to R7 body (split 24MB hA + 3MB hB, plain LB(256), no
// spills) at BSZ=512 -> 19.3KB LDS -> 8 blocks/CU naturally (VGPR~52<64).
// (b) NEW k_srt: in-place per-bucket 48-slice counting sort by src. Every
// eagg block then sweeps the 24MB table monotonically; co-resident blocks
// advance in loose lockstep -> ~1-2MB sliding window fits per-XCD L2 ->
// each line fetched ~once per XCD instead of ~32 misses. Fixed-point LDS
// aggregation is order-independent -> bit-identical result.

#define NNODES 1500000
#define NEDGES 12000000
#define NTRACK 250000
#define BSH    9           // log2(bucket size)
#define BSZ    512         // nodes per agg bucket
#define BMASK  511u
#define NBUCK  2930        // ceil(NNODES/512)
#define PCHUNK 4096        // edges per k_part block (LDS-sorted)
#define PBLK   2930        // ceil(NEDGES/PCHUNK)
#define HCHUNK 32768       // edges per k_bhist block
#define HBLK   367         // ceil(NEDGES/HCHUNK)
#define SRCMASK 0x1FFFFFu  // 21 bits
#define NSLICE 48          // src slices (src>>15, 512KB of hA each)
#define SRTR   20          // k_srt records/thread (covers runs to 5120)
#define FXSCALE 16777216.f // 2^24
#define FXINV   (1.f / 16777216.f)

typedef unsigned int   u32;
typedef unsigned short u16;

static __device__ __forceinline__ float b2f(u32 v) {
    union { float f; u32 u; } x; x.u = v << 16; return x.f;
}
static __device__ __forceinline__ u16 f2b(float f) {
    __hip_bfloat16 h = __float2bfloat16(f);
    return *reinterpret_cast<u16*>(&h);
}
static __device__ __forceinline__ float ldw(const void* p, int i, int isf32) {
    return isf32 ? ((const float*)p)[i] : b2f((u32)((const u16*)p)[i]);
}
static __device__ __forceinline__ int fx(float f) {
    return (int)rintf(f * FXSCALE);
}

// ---------------- dtype probe ----------------

__global__ void k_detect(const u16* a, const u16* b, const u16* c,
                         const u16* d, const u16* e, const u16* f,
                         int* flag) {
    if (blockIdx.x == 0 && threadIdx.x == 0) {
        int isf32 = 0;
        const u16* ps[6] = {a, b, c, d, e, f};
        const int  ns[6] = {9, 9, 9, 9, 9, 8};
        for (int k = 0; k < 6; k++)
            for (int i = 0; i < ns[k]; i++) {
                float v = b2f((u32)ps[k][i]);
                if (!(fabsf(v) < 1.0e3f)) isf32 = 1;   // catches NaN/Inf too
            }
        *flag = isf32;
    }
}

// ------------- x -> bf16 table (3 MB, fits per-XCD L2 for layer 1) -------

__global__ __launch_bounds__(256) void k_xcast(const void* __restrict__ x,
                                               u16* __restrict__ xb,
                                               const int* __restrict__ flag) {
    int isf32 = *flag;
    int n = blockIdx.x * 256 + threadIdx.x;
    if (n < NNODES)
        xb[n] = isf32 ? f2b(((const float*)x)[n]) : ((const u16*)x)[n];
}

// ---------------- bucket histogram + scan (exact, unpadded) --------------

__global__ __launch_bounds__(512) void k_bhist(const int* __restrict__ dst,
                                               int* __restrict__ gh) {
    __shared__ u32 h[NBUCK];
    int t = threadIdx.x;
    for (int b = t; b < NBUCK; b += 512) h[b] = 0;
    __syncthreads();
    int c0 = blockIdx.x * HCHUNK;
#pragma unroll 4
    for (int i = 0; i < HCHUNK / 512; i++) {
        int e = c0 + i * 512 + t;
        if (e < NEDGES) atomicAdd(&h[((u32)dst[e]) >> BSH], 1u);
    }
    __syncthreads();
    for (int b = t; b < NBUCK; b += 512) {
        u32 c = h[b];
        if (c) atomicAdd((u32*)&gh[b], c);
    }
}

__global__ __launch_bounds__(256) void k_bscan(const int* __restrict__ gh,
                                               int* __restrict__ bstart,
                                               int* __restrict__ gcur) {
    __shared__ u32 sd[256];
    __shared__ u32 carry;
    int t = threadIdx.x;
    if (t == 0) carry = 0;
    __syncthreads();
    for (int c0 = 0; c0 < NBUCK; c0 += 256) {
        int b = c0 + t;
        u32 v = (b < NBUCK) ? (u32)gh[b] : 0;
        sd[t] = v; __syncthreads();
        for (int o = 1; o < 256; o <<= 1) {
            u32 a = (t >= o) ? sd[t - o] : 0;
            __syncthreads();
            sd[t] += a;
            __syncthreads();
        }
        u32 excl = carry + sd[t] - v;
        if (b < NBUCK) { bstart[b] = (int)excl; gcur[b] = (int)excl; }
        __syncthreads();
        if (t == 255) carry += sd[255];
        __syncthreads();
    }
    if (t == 0) bstart[NBUCK] = NEDGES;
}

// ---- partition: chunk-local LDS counting sort + ordered coalesced flush ----
// LDS: cur 11.7K + gbA 11.7K + rec 32K + sd 2K = 57.4KB. Flush resolves each
// slot's bucket by binary search over cur[] (post-phase-3 = END offsets).

__global__ __launch_bounds__(512) void k_part(const int* __restrict__ src,
                                              const int* __restrict__ dst,
                                              const void* __restrict__ attr,
                                              int* __restrict__ gcur,
                                              uint2* __restrict__ perm,
                                              const int* __restrict__ flag) {
    __shared__ int   cur[NBUCK];    // hist -> local exclusive start -> cursor
    __shared__ int   gbA[NBUCK];    // global run base minus local start
    __shared__ uint2 rec[PCHUNK];   // bucket-grouped records
    __shared__ u32   sd[512];
    __shared__ u32   carryS;
    int isf32 = *flag;
    int t = threadIdx.x;
    int c0 = blockIdx.x * PCHUNK;
    int chunkN = NEDGES - c0; if (chunkN > PCHUNK) chunkN = PCHUNK;

    for (int b = t; b < NBUCK; b += 512) cur[b] = 0;
    if (t == 0) carryS = 0;
    __syncthreads();

    // phase 1: histogram; keep src/dst in registers
    int ds_[8], sr_[8];
#pragma unroll
    for (int k = 0; k < 8; k++) {
        int e = c0 + k * 512 + t;
        if (e < NEDGES) {
            ds_[k] = dst[e];
            sr_[k] = src[e];
            atomicAdd((u32*)&cur[((u32)ds_[k]) >> BSH], 1u);
        } else { ds_[k] = -1; sr_[k] = 0; }
    }
    __syncthreads();

    // phase 2: exclusive scan of cur + global run reservation
    for (int b0 = 0; b0 < NBUCK; b0 += 512) {
        int b = b0 + t;
        u32 v = (b < NBUCK) ? (u32)cur[b] : 0;
        sd[t] = v; __syncthreads();
        for (int o = 1; o < 512; o <<= 1) {
            u32 a = (t >= o) ? sd[t - o] : 0;
            __syncthreads();
            sd[t] += a;
            __syncthreads();
        }
        u32 excl = carryS + sd[t] - v;
        if (b < NBUCK) {
            cur[b] = (int)excl;
            if (v) gbA[b] = atomicAdd(&gcur[b], (int)v) - (int)excl;
        }
        __syncthreads();
        if (t == 511) carryS += sd[511];
        __syncthreads();
    }

    // phase 3: scatter records into LDS
#pragma unroll
    for (int k = 0; k < 8; k++) {
        int e = c0 + k * 512 + t;
        if (e < NEDGES) {
            u32 d  = (u32)ds_[k];
            u32 fb = d >> BSH;
            u32 ap;
            if (isf32) {
                float2 a = ((const float2*)attr)[e];
                ap = (u32)f2b(a.x) | ((u32)f2b(a.y) << 16);
            } else {
                ap = ((const u32*)attr)[e];
            }
            int slot = atomicAdd(&cur[fb], 1);
            uint2 r; r.x = ((u32)sr_[k]) | ((d & BMASK) << 21); r.y = ap;
            rec[slot] = r;
        }
    }
    __syncthreads();

    // phase 4: ordered flush -- slot-consecutive => line-burst writes.
#pragma unroll
    for (int j = 0; j < 8; j++) {
        int s = j * 512 + t;
        if (s < chunkN) {
            int lo = 0, hi = NBUCK - 1;
            while (lo < hi) {
                int mid = (lo + hi) >> 1;
                if (cur[mid] > s) hi = mid; else lo = mid + 1;
            }
            perm[gbA[lo] + s] = rec[s];
        }
    }
}

// ---- k_srt: in-place per-bucket counting sort by src slice (src>>15) ----
// Makes every eagg block sweep the gather table monotonically -> co-resident
// blocks share a sliding ~1-2MB window that fits per-XCD L2.

__global__ __launch_bounds__(256) void k_srt(const int* __restrict__ bstart,
                                             uint2* __restrict__ perm) {
    __shared__ int h[NSLICE];
    int t = threadIdx.x;
    int b = blockIdx.x;
    int r0 = bstart[b], r1 = bstart[b + 1];
    int len = r1 - r0;
    if (len <= 0) return;                 // uniform branch
    if (len > SRTR * 256) return;         // safety: leave bucket unsorted
    if (t < NSLICE) h[t] = 0;
    __syncthreads();

    uint2 r[SRTR];
#pragma unroll
    for (int k = 0; k < SRTR; k++) {
        int i = r0 + k * 256 + t;
        if (i < r1) {
            r[k] = perm[i];
            atomicAdd(&h[(r[k].x & SRCMASK) >> 15], 1);
        } else {
            r[k].x = 0xFFFFFFFFu;         // rec.x < 2^30 => safe sentinel
        }
    }
    __syncthreads();                      // all reads done before any write

    if (t == 0) {
        int s = 0;
        for (int k = 0; k < NSLICE; k++) { int c = h[k]; h[k] = s; s += c; }
    }
    __syncthreads();

#pragma unroll
    for (int k = 0; k < SRTR; k++) {
        if (r[k].x != 0xFFFFFFFFu) {
            int slot = atomicAdd(&h[(r[k].x & SRCMASK) >> 15], 1);
            perm[r0 + slot] = r[k];       // scatter within 36KB window: L2-merged
        }
    }
}

// ---- layer 1 (edge-centric): gather bf16 x (L2-resident), fx LDS acc ----

__global__ __launch_bounds__(256) void k_eagg1(
        const int* __restrict__ bstart, const uint2* __restrict__ perm,
        const u16* __restrict__ xb,
        const void* Wx, const void* bx, const void* We, const void* be,
        const void* Wo, const void* bo, const void* Wxn, const void* bxn,
        uint4* __restrict__ hA, u16* __restrict__ hB,
        const int* __restrict__ flag) {
    __shared__ int acc[BSZ * 9];
    __shared__ float sWx[9], sbx[9], sWe[18], sbe[9], sWo[81], sbo[9], sWxn[81], sbxn[9];
    int isf32 = *flag;
    int t = threadIdx.x;
    if (t < 9)  sWx[t]  = ldw(Wx,  t, isf32);
    if (t < 9)  sbx[t]  = ldw(bx,  t, isf32);
    if (t < 18) sWe[t]  = ldw(We,  t, isf32);
    if (t < 9)  sbe[t]  = ldw(be,  t, isf32);
    if (t < 81) sWo[t]  = ldw(Wo,  t, isf32);
    if (t < 9)  sbo[t]  = ldw(bo,  t, isf32);
    if (t < 81) sWxn[t] = ldw(Wxn, t, isf32);
    if (t < 9)  sbxn[t] = ldw(bxn, t, isf32);
    for (int i = t; i < BSZ * 9; i += 256) acc[i] = 0;
    __syncthreads();

    int b = blockIdx.x;
    int r0 = bstart[b], r1 = bstart[b + 1];
    for (int i = r0 + t; i < r1; i += 256) {
        uint2 rec = perm[i];
        int   l   = (int)((rec.x >> 21) & BMASK);
        float xs  = b2f((u32)xb[rec.x & SRCMASK]);
        float a0  = b2f(rec.y & 0xffffu);
        float a1  = b2f(rec.y >> 16);
        int* ap = &acc[l * 9];
#pragma unroll
        for (int j = 0; j < 9; j++) {
            float e  = fmaf(a0, sWe[2 * j], fmaf(a1, sWe[2 * j + 1], sbe[j]));
            float hh = fmaf(xs, sWx[j], sbx[j]);
            atomicAdd(&ap[j], fx(hh * e));     // native ds_add_u32
        }
    }
    __syncthreads();

    for (int l = t; l < BSZ; l += 256) {
        int n = b * BSZ + l;
        if (n >= NNODES) break;
        float av[9];
#pragma unroll
        for (int j = 0; j < 9; j++) av[j] = (float)acc[l * 9 + j] * FXINV;
        float o[9];
#pragma unroll
        for (int k = 0; k < 9; k++) {
            float v = sbo[k];
#pragma unroll
            for (int j = 0; j < 9; j++) v = fmaf(av[j], sWo[k * 9 + j], v);
            o[k] = fmaxf(v, 0.f);
        }
        u16 hv[9];
#pragma unroll
        for (int j = 0; j < 9; j++) {
            float v = sbxn[j];
#pragma unroll
            for (int k = 0; k < 9; k++) v = fmaf(o[k], sWxn[j * 9 + k], v);
            hv[j] = f2b(v);
        }
        uint4 q;
        q.x = (u32)hv[0] | ((u32)hv[1] << 16);
        q.y = (u32)hv[2] | ((u32)hv[3] << 16);
        q.z = (u32)hv[4] | ((u32)hv[5] << 16);
        q.w = (u32)hv[6] | ((u32)hv[7] << 16);
        hA[n] = q;
        hB[n] = hv[8];
    }
}

// ---- layers 2/3 (edge-centric): gather 16B+2B split tables, fx LDS acc ----

template <int OUTF, bool FUSE_NEXT>
__global__ __launch_bounds__(256) void k_eagg(
        const int* __restrict__ bstart, const uint2* __restrict__ perm,
        const uint4* __restrict__ hA, const u16* __restrict__ hB,
        const void* We, const void* be, const void* Wo, const void* bo,
        const void* Wxn, const void* bxn,
        uint4* __restrict__ oA, u16* __restrict__ oB,
        const int* __restrict__ flag) {
    __shared__ int acc[BSZ * 9];
    __shared__ float sWe[18], sbe[9], sWo[OUTF * 9], sbo[OUTF];
    __shared__ float sWxn[FUSE_NEXT ? 81 : 1], sbxn[FUSE_NEXT ? 9 : 1];
    int isf32 = *flag;
    int t = threadIdx.x;
    if (t < 18)       sWe[t] = ldw(We, t, isf32);
    if (t < 9)        sbe[t] = ldw(be, t, isf32);
    if (t < OUTF * 9) sWo[t] = ldw(Wo, t, isf32);
    if (t < OUTF)     sbo[t] = ldw(bo, t, isf32);
    if constexpr (FUSE_NEXT) {
        if (t < 81) sWxn[t] = ldw(Wxn, t, isf32);
        if (t < 9)  sbxn[t] = ldw(bxn, t, isf32);
    }
    for (int i = t; i < BSZ * 9; i += 256) acc[i] = 0;
    __syncthreads();

    int b = blockIdx.x;
    int r0 = bstart[b], r1 = bstart[b + 1];
    for (int i = r0 + t; i < r1; i += 256) {
        uint2 rec = perm[i];
        int   s   = (int)(rec.x & SRCMASK);
        int   l   = (int)((rec.x >> 21) & BMASK);
        float a0  = b2f(rec.y & 0xffffu);
        float a1  = b2f(rec.y >> 16);
        uint4 qa  = hA[s];
        u32   qb  = (u32)hB[s];
        float ev[9];
#pragma unroll
        for (int j = 0; j < 9; j++)
            ev[j] = fmaf(a0, sWe[2 * j], fmaf(a1, sWe[2 * j + 1], sbe[j]));
        float h[9];
        h[0] = b2f(qa.x & 0xffffu); h[1] = b2f(qa.x >> 16);
        h[2] = b2f(qa.y & 0xffffu); h[3] = b2f(qa.y >> 16);
        h[4] = b2f(qa.z & 0xffffu); h[5] = b2f(qa.z >> 16);
        h[6] = b2f(qa.w & 0xffffu); h[7] = b2f(qa.w >> 16);
        h[8] = b2f(qb);
        int* ap = &acc[l * 9];
#pragma unroll
        for (int j = 0; j < 9; j++)
            atomicAdd(&ap[j], fx(h[j] * ev[j]));
    }
    __syncthreads();

    for (int l = t; l < BSZ; l += 256) {
        int n = b * BSZ + l;
        if (n >= NNODES) break;
        float av[9];
#pragma unroll
        for (int j = 0; j < 9; j++) av[j] = (float)acc[l * 9 + j] * FXINV;
        float o[OUTF];
#pragma unroll
        for (int k = 0; k < OUTF; k++) {
            float v = sbo[k];
#pragma unroll
            for (int j = 0; j < 9; j++) v = fmaf(av[j], sWo[k * 9 + j], v);
            o[k] = fmaxf(v, 0.f);
        }
        if constexpr (FUSE_NEXT) {
            u16 hv[9];
#pragma unroll
            for (int j = 0; j < 9; j++) {
                float v = sbxn[j];
#pragma unroll
                for (int k = 0; k < OUTF; k++) v = fmaf(o[k], sWxn[j * 9 + k], v);
                hv[j] = f2b(v);
            }
            uint4 q;
            q.x = (u32)hv[0] | ((u32)hv[1] << 16);
            q.y = (u32)hv[2] | ((u32)hv[3] << 16);
            q.z = (u32)hv[4] | ((u32)hv[5] << 16);
            q.w = (u32)hv[6] | ((u32)hv[7] << 16);
            oA[n] = q;
            oB[n] = hv[8];
        } else {
            uint2 q;
            q.x = (u32)f2b(o[0]) | ((u32)f2b(o[1]) << 16);
            q.y = (u32)f2b(o[2]) | ((u32)f2b(o[3]) << 16);
            ((uint2*)oA)[n] = q;   // f table: 8B/node
        }
    }
}

// ---------------- head MLP + log_softmax ----------------

__global__ __launch_bounds__(256) void k_head(
        const u16* __restrict__ f,
        const void* W1, const void* b1, const void* W2, const void* b2,
        void* __restrict__ out, const int* __restrict__ flag) {
    __shared__ float sW1[192], sb1[8], sW2[32], sb2[4];
    int isf32 = *flag;
    int t = threadIdx.x;
    if (t < 192) sW1[t] = ldw(W1, t, isf32);
    if (t < 8)   sb1[t] = ldw(b1, t, isf32);
    if (t < 32)  sW2[t] = ldw(W2, t, isf32);
    if (t < 4)   sb2[t] = ldw(b2, t, isf32);
    __syncthreads();

    int tr = blockIdx.x * 256 + t;
    if (tr >= NTRACK) return;

    const uint4* fp = (const uint4*)(f + (size_t)tr * 24);
    uint4 A = fp[0], B = fp[1], C = fp[2];
    u32 w[12] = {A.x, A.y, A.z, A.w, B.x, B.y, B.z, B.w, C.x, C.y, C.z, C.w};
    float in[24];
#pragma unroll
    for (int i = 0; i < 12; i++) {
        in[2 * i]     = b2f(w[i] & 0xffffu);
        in[2 * i + 1] = b2f(w[i] >> 16);
    }

    float z1[8];
#pragma unroll
    for (int o = 0; o < 8; o++) {
        float v = sb1[o];
#pragma unroll
        for (int i = 0; i < 24; i++) v = fmaf(in[i], sW1[o * 24 + i], v);
        z1[o] = fmaxf(v, 0.f);
    }
    float z2[4];
#pragma unroll
    for (int c = 0; c < 4; c++) {
        float v = sb2[c];
#pragma unroll
        for (int o = 0; o < 8; o++) v = fmaf(z1[o], sW2[c * 8 + o], v);
        z2[c] = v;
    }
    float m = fmaxf(fmaxf(z2[0], z2[1]), fmaxf(z2[2], z2[3]));
    float s = 0.f;
#pragma unroll
    for (int c = 0; c < 4; c++) s += expf(z2[c] - m);
    float l = logf(s) + m;

    if (isf32) {
        float4 q; q.x = z2[0] - l; q.y = z2[1] - l; q.z = z2[2] - l; q.w = z2[3] - l;
        ((float4*)((float*)out + (size_t)tr * 4))[0] = q;
    } else {
        uint2 q;
        q.x = (u32)f2b(z2[0] - l) | ((u32)f2b(z2[1] - l) << 16);
        q.y = (u32)f2b(z2[2] - l) | ((u32)f2b(z2[3] - l) << 16);
        ((uint2*)((u16*)out + (size_t)tr * 4))[0] = q;
    }
}

// ---------------- host ----------------

extern "C" void kernel_launch(void* const* d_in, const int* in_sizes, int n_in,
                              void* d_out, int out_size, void* d_ws, size_t ws_size,
                              hipStream_t stream) {
    const void* X    = d_in[0];
    const int* eidx  = (const int*)d_in[1];
    const void* eattr= d_in[2];
    const void *WX1 = d_in[3],  *BX1 = d_in[4];
    const void *WE1 = d_in[5],  *BE1 = d_in[6];
    const void *WO1 = d_in[7],  *BO1 = d_in[8];
    const void *WX2 = d_in[9],  *BX2 = d_in[10];
    const void *WE2 = d_in[11], *BE2 = d_in[12];
    const void *WO2 = d_in[13], *BO2 = d_in[14];
    const void *WX3 = d_in[15], *BX3 = d_in[16];
    const void *WE3 = d_in[17], *BE3 = d_in[18];
    const void *WO3 = d_in[19], *BO3 = d_in[20];
    const void *W1  = d_in[21], *B1  = d_in[22];
    const void *W2  = d_in[23], *B2  = d_in[24];

    const int* src = eidx;
    const int* dst = eidx + NEDGES;

    // workspace layout (~150 MB)
    char* w = (char*)d_ws;
    size_t off = 0;
    auto take = [&](size_t bytes) -> void* {
        void* p = w + off;
        off += (bytes + 255) & ~(size_t)255;
        return p;
    };
    int*   flag   = (int*)take(256);
    int*   gh     = (int*)take((size_t)NBUCK * 4);
    int*   bstart = (int*)take((size_t)(NBUCK + 1) * 4);
    int*   gcur   = (int*)take((size_t)NBUCK * 4);
    u16*   xb     = (u16*)take((size_t)NNODES * 2);        // 3 MB bf16 x
    uint2* perm   = (uint2*)take((size_t)NEDGES * 8);      // 96 MB exact
    uint4* hA2    = (uint4*)take((size_t)NNODES * 16);     // 24 MB
    u16*   hB2    = (u16*)take((size_t)NNODES * 2);        // 3 MB
    uint4* hA3    = (uint4*)take((size_t)NNODES * 16);     // 24 MB
    u16*   hB3    = (u16*)take((size_t)NNODES * 2);        // 3 MB
    u16*   f      = (u16*)hA2;  // layer-3 output (12 MB) reuses hA2 (dead by then)
    (void)ws_size; (void)n_in; (void)in_sizes; (void)out_size;

    const int NB = (NNODES + 255) / 256;
    const int TB = (NTRACK + 255) / 256;

    hipMemsetAsync(gh, 0, (size_t)NBUCK * 4, stream);

    k_detect <<<1,    64,  0, stream>>>((const u16*)BX1, (const u16*)BE1, (const u16*)BO1,
                                        (const u16*)BX2, (const u16*)BE2, (const u16*)B1, flag);
    k_xcast  <<<NB,   256, 0, stream>>>(X, xb, flag);
    k_bhist  <<<HBLK, 512, 0, stream>>>(dst, gh);
    k_bscan  <<<1,    256, 0, stream>>>(gh, bstart, gcur);
    k_part   <<<PBLK, 512, 0, stream>>>(src, dst, eattr, gcur, perm, flag);
    k_srt    <<<NBUCK,256, 0, stream>>>(bstart, perm);

    k_eagg1        <<<NBUCK, 256, 0, stream>>>(bstart, perm, xb,
                                               WX1, BX1, WE1, BE1, WO1, BO1, WX2, BX2,
                                               hA2, hB2, flag);
    k_eagg<9,true> <<<NBUCK, 256, 0, stream>>>(bstart, perm, hA2, hB2,
                                               WE2, BE2, WO2, BO2, WX3, BX3,
                                               hA3, hB3, flag);
    k_eagg<4,false><<<NBUCK, 256, 0, stream>>>(bstart, perm, hA3, hB3,
                                               WE3, BE3, WO3, BO3, WO3, BO3,
                                               (uint4*)f, (u16*)f, flag);
    k_head         <<<TB,    256, 0, stream>>>(f, W1, B1, W2, B2, d_out, flag);
}

// Round 3
// 1041.715 us; speedup vs baseline: 1.5763x; 1.0017x over previous
//
#include <hip/hip_runtime.h>
#include <hip/hip_bf16.h>

// trackletGNN: 3x edge-conv + MLP head.
// R10: kill device-atomic serialization in the partition stage.
// R9 post-mortem: k_part is now the top kernel (230us) with VALU 20%,
// HBM 19%, Occ 41% -- nothing saturated => stall-bound. Dominant suspect:
// 2930 blocks x ~2200 nonempty buckets = 6.4M device-scope atomicAdds on a
// 46-line gcur[] array; ~140K atomics/line x ~2-4cyc serial = 120-230us.
// Matches measured. k_bhist had 1.07M of the same (~40us).
// R10: precompute ALL placement offsets -> zero global atomics:
//   k_hist:   cnt[chunk][bucket] u16 (17MB, coalesced rows), no atomics.
//   k_mscanA: per-segment (8) column-prefix over chunks -> off[chunk][b],
//             seg totals st[seg][b].
//   k_mscanB: one block: bucket totals -> bstart[] (replaces bhist+bscan),
//             + per-seg bases segb[seg][b] (bstart folded in).
//   k_part:   loads cnt/off/segb rows (coalesced), local scan, ONE fused
//             edge pass (phase-1 re-histogram dropped), bid[] u16 replaces
//             binary search. LDS 63.4KB static. No global atomics at all.
// k_srt + eagg kernels unchanged from R9 (proven). Fixed-point LDS
// aggregation is order-independent -> bit-identical output.

#define NNODES 1500000
#define NEDGES 12000000
#define NTRACK 250000
#define BSH    9           // log2(bucket size)
#define BSZ    512         // nodes per agg bucket
#define BMASK  511u
#define NBUCK  2930        // ceil(NNODES/512)
#define PCHUNK 4096        // edges per k_part block (LDS-sorted)
#define PBLK   2930        // ceil(NEDGES/PCHUNK)
#define NSEG   8           // chunk segments for the column scan
#define SEGC   367         // chunks per segment (8*367 >= 2930)
#define NTILE  46          // bucket tiles of 64 ((2930+63)/64)
#define SRCMASK 0x1FFFFFu  // 21 bits
#define NSLICE 48          // src slices (src>>15, 512KB of hA each)
#define SRTR   20          // k_srt records/thread (covers runs to 5120)
#define FXSCALE 16777216.f // 2^24
#define FXINV   (1.f / 16777216.f)

typedef unsigned int   u32;
typedef unsigned short u16;

static __device__ __forceinline__ float b2f(u32 v) {
    union { float f; u32 u; } x; x.u = v << 16; return x.f;
}
static __device__ __forceinline__ u16 f2b(float f) {
    __hip_bfloat16 h = __float2bfloat16(f);
    return *reinterpret_cast<u16*>(&h);
}
static __device__ __forceinline__ float ldw(const void* p, int i, int isf32) {
    return isf32 ? ((const float*)p)[i] : b2f((u32)((const u16*)p)[i]);
}
static __device__ __forceinline__ int fx(float f) {
    return (int)rintf(f * FXSCALE);
}

// ---------------- dtype probe ----------------

__global__ void k_detect(const u16* a, const u16* b, const u16* c,
                         const u16* d, const u16* e, const u16* f,
                         int* flag) {
    if (blockIdx.x == 0 && threadIdx.x == 0) {
        int isf32 = 0;
        const u16* ps[6] = {a, b, c, d, e, f};
        const int  ns[6] = {9, 9, 9, 9, 9, 8};
        for (int k = 0; k < 6; k++)
            for (int i = 0; i < ns[k]; i++) {
                float v = b2f((u32)ps[k][i]);
                if (!(fabsf(v) < 1.0e3f)) isf32 = 1;   // catches NaN/Inf too
            }
        *flag = isf32;
    }
}

// ------------- x -> bf16 table (3 MB, fits per-XCD L2 for layer 1) -------

__global__ __launch_bounds__(256) void k_xcast(const void* __restrict__ x,
                                               u16* __restrict__ xb,
                                               const int* __restrict__ flag) {
    int isf32 = *flag;
    int n = blockIdx.x * 256 + threadIdx.x;
    if (n < NNODES)
        xb[n] = isf32 ? f2b(((const float*)x)[n]) : ((const u16*)x)[n];
}

// ------- per-chunk bucket histogram -> cnt[chunk][bucket] (u16) ---------

__global__ __launch_bounds__(512) void k_hist(const int* __restrict__ dst,
                                              u16* __restrict__ cnt) {
    __shared__ u32 h[NBUCK];
    int t = threadIdx.x;
    int chunk = blockIdx.x;
    int c0 = chunk * PCHUNK;
    for (int b = t; b < NBUCK; b += 512) h[b] = 0;
    __syncthreads();
#pragma unroll
    for (int k = 0; k < 8; k++) {
        int e = c0 + k * 512 + t;
        if (e < NEDGES) atomicAdd(&h[((u32)dst[e]) >> BSH], 1u);
    }
    __syncthreads();
    size_t row = (size_t)chunk * NBUCK;
    for (int b = t; b < NBUCK; b += 512) cnt[row + b] = (u16)h[b];
}

// -- column scan over chunks (per segment): off[chunk][b], st[seg][b] ----

__global__ __launch_bounds__(64) void k_mscanA(const u16* __restrict__ cnt,
                                               u16* __restrict__ offm,
                                               u16* __restrict__ st) {
    int seg  = blockIdx.x / NTILE;
    int tile = blockIdx.x % NTILE;
    int b = tile * 64 + threadIdx.x;
    if (b >= NBUCK) return;
    int cS = seg * SEGC;
    int cE = cS + SEGC; if (cE > PBLK) cE = PBLK;
    u32 run = 0;
#pragma unroll 4
    for (int c = cS; c < cE; c++) {
        size_t idx = (size_t)c * NBUCK + b;
        u32 v = (u32)cnt[idx];
        offm[idx] = (u16)run;
        run += v;
    }
    st[(size_t)seg * NBUCK + b] = (u16)run;
}

// -- combine: bucket totals -> bstart[], per-seg bases (bstart folded) ---

__global__ __launch_bounds__(256) void k_mscanB(const u16* __restrict__ st,
                                                int* __restrict__ bstart,
                                                u32* __restrict__ segb) {
    __shared__ u32 sd[256];
    __shared__ u32 carry;
    int t = threadIdx.x;
    if (t == 0) carry = 0;
    __syncthreads();
    for (int c0 = 0; c0 < NBUCK; c0 += 256) {
        int b = c0 + t;
        u32 tot = 0;
        if (b < NBUCK)
#pragma unroll
            for (int s = 0; s < NSEG; s++) tot += (u32)st[(size_t)s * NBUCK + b];
        sd[t] = tot; __syncthreads();
        for (int o = 1; o < 256; o <<= 1) {
            u32 a = (t >= o) ? sd[t - o] : 0;
            __syncthreads();
            sd[t] += a;
            __syncthreads();
        }
        u32 excl = carry + sd[t] - tot;
        if (b < NBUCK) {
            bstart[b] = (int)excl;
            u32 r = excl;
#pragma unroll
            for (int s = 0; s < NSEG; s++) {
                segb[(size_t)s * NBUCK + b] = r;
                r += (u32)st[(size_t)s * NBUCK + b];
            }
        }
        __syncthreads();
        if (t == 255) carry += sd[255];
        __syncthreads();
    }
    if (t == 0) bstart[NBUCK] = NEDGES;
}

// ---- partition: precomputed offsets, LDS counting sort, ordered flush ----
// LDS: cur 11.7K + gbA 11.7K + rec 32K + bid 8K = 63.4KB (static, fits).
// Zero global atomics. Scan temp overlays rec (dead until edge pass).

__global__ __launch_bounds__(512) void k_part(const int* __restrict__ src,
                                              const int* __restrict__ dst,
                                              const void* __restrict__ attr,
                                              const u16* __restrict__ cnt,
                                              const u16* __restrict__ offm,
                                              const u32* __restrict__ segb,
                                              uint2* __restrict__ perm,
                                              const int* __restrict__ flag) {
    __shared__ u32   cur[NBUCK];    // cnt -> local excl start -> cursor
    __shared__ u32   gbA[NBUCK];    // global base minus local start
    __shared__ uint2 rec[PCHUNK];   // bucket-grouped records
    __shared__ u16   bid[PCHUNK];   // per-slot bucket id
    __shared__ u32   carryS;
    u32* sd = reinterpret_cast<u32*>(rec);   // 2KB scan temp overlay
    int isf32 = *flag;
    int t = threadIdx.x;
    int chunk = blockIdx.x;
    int seg = chunk / SEGC;
    int c0 = chunk * PCHUNK;
    int chunkN = NEDGES - c0; if (chunkN > PCHUNK) chunkN = PCHUNK;
    size_t row = (size_t)chunk * NBUCK;

    // load this chunk's per-bucket counts
    for (int b = t; b < NBUCK; b += 512) cur[b] = (u32)cnt[row + b];
    if (t == 0) carryS = 0;
    __syncthreads();

    // local exclusive scan (in place), temp in rec-overlay
    for (int b0 = 0; b0 < NBUCK; b0 += 512) {
        int b = b0 + t;
        u32 v = (b < NBUCK) ? cur[b] : 0;
        sd[t] = v; __syncthreads();
        for (int o = 1; o < 512; o <<= 1) {
            u32 a = (t >= o) ? sd[t - o] : 0;
            __syncthreads();
            sd[t] += a;
            __syncthreads();
        }
        u32 excl = carryS + sd[t] - v;
        if (b < NBUCK) cur[b] = excl;
        __syncthreads();
        if (t == 511) carryS += sd[511];
        __syncthreads();
    }

    // global base minus local start (all precomputed, coalesced reads)
    for (int b = t; b < NBUCK; b += 512)
        gbA[b] = segb[(size_t)seg * NBUCK + b] + (u32)offm[row + b] - cur[b];
    __syncthreads();

    // fused edge pass: read, pack, scatter into LDS by bucket
#pragma unroll
    for (int k = 0; k < 8; k++) {
        int e = c0 + k * 512 + t;
        if (e < NEDGES) {
            u32 d = (u32)dst[e];
            u32 s = (u32)src[e];
            u32 fb = d >> BSH;
            u32 ap;
            if (isf32) {
                float2 a = ((const float2*)attr)[e];
                ap = (u32)f2b(a.x) | ((u32)f2b(a.y) << 16);
            } else {
                ap = ((const u32*)attr)[e];
            }
            int slot = (int)atomicAdd(&cur[fb], 1u);
            uint2 r; r.x = s | ((d & BMASK) << 21); r.y = ap;
            rec[slot] = r;
            bid[slot] = (u16)fb;
        }
    }
    __syncthreads();

    // ordered flush: ascending slot = ascending global address per bucket
#pragma unroll
    for (int j = 0; j < 8; j++) {
        int s = j * 512 + t;
        if (s < chunkN) {
            u32 fb = (u32)bid[s];
            perm[gbA[fb] + s] = rec[s];
        }
    }
}

// ---- k_srt: in-place per-bucket counting sort by src slice (src>>15) ----
// Makes every eagg block sweep the gather table monotonically -> co-resident
// blocks share a sliding ~1-2MB window that fits per-XCD L2.

__global__ __launch_bounds__(256) void k_srt(const int* __restrict__ bstart,
                                             uint2* __restrict__ perm) {
    __shared__ int h[NSLICE];
    int t = threadIdx.x;
    int b = blockIdx.x;
    int r0 = bstart[b], r1 = bstart[b + 1];
    int len = r1 - r0;
    if (len <= 0) return;                 // uniform branch
    if (len > SRTR * 256) return;         // safety: leave bucket unsorted
    if (t < NSLICE) h[t] = 0;
    __syncthreads();

    uint2 r[SRTR];
#pragma unroll
    for (int k = 0; k < SRTR; k++) {
        int i = r0 + k * 256 + t;
        if (i < r1) {
            r[k] = perm[i];
            atomicAdd(&h[(r[k].x & SRCMASK) >> 15], 1);
        } else {
            r[k].x = 0xFFFFFFFFu;         // rec.x < 2^30 => safe sentinel
        }
    }
    __syncthreads();                      // all reads done before any write

    if (t == 0) {
        int s = 0;
        for (int k = 0; k < NSLICE; k++) { int c = h[k]; h[k] = s; s += c; }
    }
    __syncthreads();

#pragma unroll
    for (int k = 0; k < SRTR; k++) {
        if (r[k].x != 0xFFFFFFFFu) {
            int slot = atomicAdd(&h[(r[k].x & SRCMASK) >> 15], 1);
            perm[r0 + slot] = r[k];       // scatter within 36KB window: L2-merged
        }
    }
}

// ---- layer 1 (edge-centric): gather bf16 x (L2-resident), fx LDS acc ----

__global__ __launch_bounds__(256) void k_eagg1(
        const int* __restrict__ bstart, const uint2* __restrict__ perm,
        const u16* __restrict__ xb,
        const void* Wx, const void* bx, const void* We, const void* be,
        const void* Wo, const void* bo, const void* Wxn, const void* bxn,
        uint4* __restrict__ hA, u16* __restrict__ hB,
        const int* __restrict__ flag) {
    __shared__ int acc[BSZ * 9];
    __shared__ float sWx[9], sbx[9], sWe[18], sbe[9], sWo[81], sbo[9], sWxn[81], sbxn[9];
    int isf32 = *flag;
    int t = threadIdx.x;
    if (t < 9)  sWx[t]  = ldw(Wx,  t, isf32);
    if (t < 9)  sbx[t]  = ldw(bx,  t, isf32);
    if (t < 18) sWe[t]  = ldw(We,  t, isf32);
    if (t < 9)  sbe[t]  = ldw(be,  t, isf32);
    if (t < 81) sWo[t]  = ldw(Wo,  t, isf32);
    if (t < 9)  sbo[t]  = ldw(bo,  t, isf32);
    if (t < 81) sWxn[t] = ldw(Wxn, t, isf32);
    if (t < 9)  sbxn[t] = ldw(bxn, t, isf32);
    for (int i = t; i < BSZ * 9; i += 256) acc[i] = 0;
    __syncthreads();

    int b = blockIdx.x;
    int r0 = bstart[b], r1 = bstart[b + 1];
    for (int i = r0 + t; i < r1; i += 256) {
        uint2 rec = perm[i];
        int   l   = (int)((rec.x >> 21) & BMASK);
        float xs  = b2f((u32)xb[rec.x & SRCMASK]);
        float a0  = b2f(rec.y & 0xffffu);
        float a1  = b2f(rec.y >> 16);
        int* ap = &acc[l * 9];
#pragma unroll
        for (int j = 0; j < 9; j++) {
            float e  = fmaf(a0, sWe[2 * j], fmaf(a1, sWe[2 * j + 1], sbe[j]));
            float hh = fmaf(xs, sWx[j], sbx[j]);
            atomicAdd(&ap[j], fx(hh * e));     // native ds_add_u32
        }
    }
    __syncthreads();

    for (int l = t; l < BSZ; l += 256) {
        int n = b * BSZ + l;
        if (n >= NNODES) break;
        float av[9];
#pragma unroll
        for (int j = 0; j < 9; j++) av[j] = (float)acc[l * 9 + j] * FXINV;
        float o[9];
#pragma unroll
        for (int k = 0; k < 9; k++) {
            float v = sbo[k];
#pragma unroll
            for (int j = 0; j < 9; j++) v = fmaf(av[j], sWo[k * 9 + j], v);
            o[k] = fmaxf(v, 0.f);
        }
        u16 hv[9];
#pragma unroll
        for (int j = 0; j < 9; j++) {
            float v = sbxn[j];
#pragma unroll
            for (int k = 0; k < 9; k++) v = fmaf(o[k], sWxn[j * 9 + k], v);
            hv[j] = f2b(v);
        }
        uint4 q;
        q.x = (u32)hv[0] | ((u32)hv[1] << 16);
        q.y = (u32)hv[2] | ((u32)hv[3] << 16);
        q.z = (u32)hv[4] | ((u32)hv[5] << 16);
        q.w = (u32)hv[6] | ((u32)hv[7] << 16);
        hA[n] = q;
        hB[n] = hv[8];
    }
}

// ---- layers 2/3 (edge-centric): gather 16B+2B split tables, fx LDS acc ----

template <int OUTF, bool FUSE_NEXT>
__global__ __launch_bounds__(256) void k_eagg(
        const int* __restrict__ bstart, const uint2* __restrict__ perm,
        const uint4* __restrict__ hA, const u16* __restrict__ hB,
        const void* We, const void* be, const void* Wo, const void* bo,
        const void* Wxn, const void* bxn,
        uint4* __restrict__ oA, u16* __restrict__ oB,
        const int* __restrict__ flag) {
    __shared__ int acc[BSZ * 9];
    __shared__ float sWe[18], sbe[9], sWo[OUTF * 9], sbo[OUTF];
    __shared__ float sWxn[FUSE_NEXT ? 81 : 1], sbxn[FUSE_NEXT ? 9 : 1];
    int isf32 = *flag;
    int t = threadIdx.x;
    if (t < 18)       sWe[t] = ldw(We, t, isf32);
    if (t < 9)        sbe[t] = ldw(be, t, isf32);
    if (t < OUTF * 9) sWo[t] = ldw(Wo, t, isf32);
    if (t < OUTF)     sbo[t] = ldw(bo, t, isf32);
    if constexpr (FUSE_NEXT) {
        if (t < 81) sWxn[t] = ldw(Wxn, t, isf32);
        if (t < 9)  sbxn[t] = ldw(bxn, t, isf32);
    }
    for (int i = t; i < BSZ * 9; i += 256) acc[i] = 0;
    __syncthreads();

    int b = blockIdx.x;
    int r0 = bstart[b], r1 = bstart[b + 1];
    for (int i = r0 + t; i < r1; i += 256) {
        uint2 rec = perm[i];
        int   s   = (int)(rec.x & SRCMASK);
        int   l   = (int)((rec.x >> 21) & BMASK);
        float a0  = b2f(rec.y & 0xffffu);
        float a1  = b2f(rec.y >> 16);
        uint4 qa  = hA[s];
        u32   qb  = (u32)hB[s];
        float ev[9];
#pragma unroll
        for (int j = 0; j < 9; j++)
            ev[j] = fmaf(a0, sWe[2 * j], fmaf(a1, sWe[2 * j + 1], sbe[j]));
        float h[9];
        h[0] = b2f(qa.x & 0xffffu); h[1] = b2f(qa.x >> 16);
        h[2] = b2f(qa.y & 0xffffu); h[3] = b2f(qa.y >> 16);
        h[4] = b2f(qa.z & 0xffffu); h[5] = b2f(qa.z >> 16);
        h[6] = b2f(qa.w & 0xffffu); h[7] = b2f(qa.w >> 16);
        h[8] = b2f(qb);
        int* ap = &acc[l * 9];
#pragma unroll
        for (int j = 0; j < 9; j++)
            atomicAdd(&ap[j], fx(h[j] * ev[j]));
    }
    __syncthreads();

    for (int l = t; l < BSZ; l += 256) {
        int n = b * BSZ + l;
        if (n >= NNODES) break;
        float av[9];
#pragma unroll
        for (int j = 0; j < 9; j++) av[j] = (float)acc[l * 9 + j] * FXINV;
        float o[OUTF];
#pragma unroll
        for (int k = 0; k < OUTF; k++) {
            float v = sbo[k];
#pragma unroll
            for (int j = 0; j < 9; j++) v = fmaf(av[j], sWo[k * 9 + j], v);
            o[k] = fmaxf(v, 0.f);
        }
        if constexpr (FUSE_NEXT) {
            u16 hv[9];
#pragma unroll
            for (int j = 0; j < 9; j++) {
                float v = sbxn[j];
#pragma unroll
                for (int k = 0; k < OUTF; k++) v = fmaf(o[k], sWxn[j * 9 + k], v);
                hv[j] = f2b(v);
            }
            uint4 q;
            q.x = (u32)hv[0] | ((u32)hv[1] << 16);
            q.y = (u32)hv[2] | ((u32)hv[3] << 16);
            q.z = (u32)hv[4] | ((u32)hv[5] << 16);
            q.w = (u32)hv[6] | ((u32)hv[7] << 16);
            oA[n] = q;
            oB[n] = hv[8];
        } else {
            uint2 q;
            q.x = (u32)f2b(o[0]) | ((u32)f2b(o[1]) << 16);
            q.y = (u32)f2b(o[2]) | ((u32)f2b(o[3]) << 16);
            ((uint2*)oA)[n] = q;   // f table: 8B/node
        }
    }
}

// ---------------- head MLP + log_softmax ----------------

__global__ __launch_bounds__(256) void k_head(
        const u16* __restrict__ f,
        const void* W1, const void* b1, const void* W2, const void* b2,
        void* __restrict__ out, const int* __restrict__ flag) {
    __shared__ float sW1[192], sb1[8], sW2[32], sb2[4];
    int isf32 = *flag;
    int t = threadIdx.x;
    if (t < 192) sW1[t] = ldw(W1, t, isf32);
    if (t < 8)   sb1[t] = ldw(b1, t, isf32);
    if (t < 32)  sW2[t] = ldw(W2, t, isf32);
    if (t < 4)   sb2[t] = ldw(b2, t, isf32);
    __syncthreads();

    int tr = blockIdx.x * 256 + t;
    if (tr >= NTRACK) return;

    const uint4* fp = (const uint4*)(f + (size_t)tr * 24);
    uint4 A = fp[0], B = fp[1], C = fp[2];
    u32 w[12] = {A.x, A.y, A.z, A.w, B.x, B.y, B.z, B.w, C.x, C.y, C.z, C.w};
    float in[24];
#pragma unroll
    for (int i = 0; i < 12; i++) {
        in[2 * i]     = b2f(w[i] & 0xffffu);
        in[2 * i + 1] = b2f(w[i] >> 16);
    }

    float z1[8];
#pragma unroll
    for (int o = 0; o < 8; o++) {
        float v = sb1[o];
#pragma unroll
        for (int i = 0; i < 24; i++) v = fmaf(in[i], sW1[o * 24 + i], v);
        z1[o] = fmaxf(v, 0.f);
    }
    float z2[4];
#pragma unroll
    for (int c = 0; c < 4; c++) {
        float v = sb2[c];
#pragma unroll
        for (int o = 0; o < 8; o++) v = fmaf(z1[o], sW2[c * 8 + o], v);
        z2[c] = v;
    }
    float m = fmaxf(fmaxf(z2[0], z2[1]), fmaxf(z2[2], z2[3]));
    float s = 0.f;
#pragma unroll
    for (int c = 0; c < 4; c++) s += expf(z2[c] - m);
    float l = logf(s) + m;

    if (isf32) {
        float4 q; q.x = z2[0] - l; q.y = z2[1] - l; q.z = z2[2] - l; q.w = z2[3] - l;
        ((float4*)((float*)out + (size_t)tr * 4))[0] = q;
    } else {
        uint2 q;
        q.x = (u32)f2b(z2[0] - l) | ((u32)f2b(z2[1] - l) << 16);
        q.y = (u32)f2b(z2[2] - l) | ((u32)f2b(z2[3] - l) << 16);
        ((uint2*)((u16*)out + (size_t)tr * 4))[0] = q;
    }
}

// ---------------- host ----------------

extern "C" void kernel_launch(void* const* d_in, const int* in_sizes, int n_in,
                              void* d_out, int out_size, void* d_ws, size_t ws_size,
                              hipStream_t stream) {
    const void* X    = d_in[0];
    const int* eidx  = (const int*)d_in[1];
    const void* eattr= d_in[2];
    const void *WX1 = d_in[3],  *BX1 = d_in[4];
    const void *WE1 = d_in[5],  *BE1 = d_in[6];
    const void *WO1 = d_in[7],  *BO1 = d_in[8];
    const void *WX2 = d_in[9],  *BX2 = d_in[10];
    const void *WE2 = d_in[11], *BE2 = d_in[12];
    const void *WO2 = d_in[13], *BO2 = d_in[14];
    const void *WX3 = d_in[15], *BX3 = d_in[16];
    const void *WE3 = d_in[17], *BE3 = d_in[18];
    const void *WO3 = d_in[19], *BO3 = d_in[20];
    const void *W1  = d_in[21], *B1  = d_in[22];
    const void *W2  = d_in[23], *B2  = d_in[24];

    const int* src = eidx;
    const int* dst = eidx + NEDGES;

    // workspace layout (~188 MB)
    char* w = (char*)d_ws;
    size_t off = 0;
    auto take = [&](size_t bytes) -> void* {
        void* p = w + off;
        off += (bytes + 255) & ~(size_t)255;
        return p;
    };
    int*   flag   = (int*)take(256);
    int*   bstart = (int*)take((size_t)(NBUCK + 1) * 4);
    u16*   cnt    = (u16*)take((size_t)PBLK * NBUCK * 2);   // 17.2 MB
    u16*   offm   = (u16*)take((size_t)PBLK * NBUCK * 2);   // 17.2 MB
    u16*   st     = (u16*)take((size_t)NSEG * NBUCK * 2);   // 47 KB
    u32*   segb   = (u32*)take((size_t)NSEG * NBUCK * 4);   // 94 KB
    u16*   xb     = (u16*)take((size_t)NNODES * 2);         // 3 MB bf16 x
    uint2* perm   = (uint2*)take((size_t)NEDGES * 8);       // 96 MB exact
    uint4* hA2    = (uint4*)take((size_t)NNODES * 16);      // 24 MB
    u16*   hB2    = (u16*)take((size_t)NNODES * 2);         // 3 MB
    uint4* hA3    = (uint4*)take((size_t)NNODES * 16);      // 24 MB
    u16*   hB3    = (u16*)take((size_t)NNODES * 2);         // 3 MB
    u16*   f      = (u16*)hA2;  // layer-3 output (12 MB) reuses hA2 (dead by then)
    (void)ws_size; (void)n_in; (void)in_sizes; (void)out_size;

    const int NB = (NNODES + 255) / 256;
    const int TB = (NTRACK + 255) / 256;

    k_detect <<<1,    64,  0, stream>>>((const u16*)BX1, (const u16*)BE1, (const u16*)BO1,
                                        (const u16*)BX2, (const u16*)BE2, (const u16*)B1, flag);
    k_xcast  <<<NB,   256, 0, stream>>>(X, xb, flag);
    k_hist   <<<PBLK, 512, 0, stream>>>(dst, cnt);
    k_mscanA <<<NSEG * NTILE, 64, 0, stream>>>(cnt, offm, st);
    k_mscanB <<<1,    256, 0, stream>>>(st, bstart, segb);
    k_part   <<<PBLK, 512, 0, stream>>>(src, dst, eattr, cnt, offm, segb, perm, flag);
    k_srt    <<<NBUCK,256, 0, stream>>>(bstart, perm);

    k_eagg1        <<<NBUCK, 256, 0, stream>>>(bstart, perm, xb,
                                               WX1, BX1, WE1, BE1, WO1, BO1, WX2, BX2,
                                               hA2, hB2, flag);
    k_eagg<9,true> <<<NBUCK, 256, 0, stream>>>(bstart, perm, hA2, hB2,
                                               WE2, BE2, WO2, BO2, WX3, BX3,
                                               hA3, hB3, flag);
    k_eagg<4,false><<<NBUCK, 256, 0, stream>>>(bstart, perm, hA3, hB3,
                                               WE3, BE3, WO3, BO3, WO3, BO3,
                                               (uint4*)f, (u16*)f, flag);
    k_head         <<<TB,    256, 0, stream>>>(f, W1, B1, W2, B2, d_out, flag);
}